// Round 9
// baseline (327.956 us; speedup 1.0000x reference)
//
#include <hip/hip_runtime.h>
#include <math.h>

typedef __attribute__((ext_vector_type(8))) short short8;
typedef __attribute__((ext_vector_type(4))) float f32x4;
typedef __attribute__((ext_vector_type(16))) float f32x16;
typedef __attribute__((ext_vector_type(4))) float fvec4;
typedef __attribute__((ext_vector_type(4))) unsigned short us4;
typedef __attribute__((ext_vector_type(2))) unsigned int uint2v;

#define DI __device__ __forceinline__
#define BARX asm volatile("s_barrier" ::: "memory")
#define WAITV6 asm volatile("s_waitcnt vmcnt(6)" ::: "memory")
#define WAITV0 asm volatile("s_waitcnt vmcnt(0)" ::: "memory")
#define WAITL0 asm volatile("s_waitcnt lgkmcnt(0)" ::: "memory")
#define SCHED0 __builtin_amdgcn_sched_barrier(0)

constexpr int BB = 2, SS = 2048, HIDc = 2048, NHc = 16, HDc = 128;
constexpr int MT = BB * SS;     // 4096 tokens
constexpr int KC = HIDc;        // 2048 inner dim

// ---- workspace layout (bytes) ----
constexpr size_t OFF_HB  = 0;                                      // H bf16   [4096][2048]
constexpr size_t OFF_WB  = OFF_HB + (size_t)MT * KC * 2;           // W bf16   4x[2048][2048]
constexpr size_t OFF_Q   = OFF_WB + (size_t)4 * HIDc * KC * 2;     // Q bf16   [b][h][s][d]
constexpr size_t OFF_K   = OFF_Q  + (size_t)BB * NHc * SS * HDc * 2;
constexpr size_t OFF_V   = OFF_K  + (size_t)BB * NHc * SS * HDc * 2; // V bf16 [b][h][d][s]
constexpr size_t OFF_ATT = OFF_V  + (size_t)BB * NHc * SS * HDc * 2; // attn bf16 [b*s][hid]
constexpr size_t OFF_COS = OFF_ATT + (size_t)MT * HIDc * 2;
constexpr size_t OFF_SIN = OFF_COS + (size_t)SS * 32 * 4;
constexpr size_t WS_NEED = OFF_SIN + (size_t)SS * 32 * 4;          // ~118 MB

DI float bf2f(unsigned short u) { union { unsigned u; float f; } v; v.u = (unsigned)u << 16; return v.f; }
DI unsigned short f2bf(float f) {
  union { float f; unsigned u; } v; v.f = f;
  unsigned r = v.u + 0x7fffu + ((v.u >> 16) & 1u);
  return (unsigned short)(r >> 16);
}

DI void gload_lds16(const void* g, void* l) {
  __builtin_amdgcn_global_load_lds((const __attribute__((address_space(1))) void*)g,
                                   (__attribute__((address_space(3))) void*)l, 16, 0, 0);
}

DI unsigned cvtpk_bf16(float lo, float hi_) {
  unsigned r;
  asm("v_cvt_pk_bf16_f32 %0, %1, %2" : "=v"(r) : "v"(lo), "v"(hi_));
  return r;
}

// ---------------------------------------------------------------------------
// 1) fp32 -> bf16 convert of H and the 4 weights into one contiguous region
// ---------------------------------------------------------------------------
__global__ void __launch_bounds__(256) cvt_kernel(
    const float* __restrict__ H,  const float* __restrict__ W0,
    const float* __restrict__ W1, const float* __restrict__ W2,
    const float* __restrict__ W3, unsigned short* __restrict__ dst)
{
  constexpr size_t HN = (size_t)MT * KC;      // 8388608
  constexpr size_t WN = (size_t)HIDc * KC;    // 4194304 = 2^22
  size_t e0 = ((size_t)blockIdx.x * 256 + threadIdx.x) * 8;
  const float* src; size_t off;
  if (e0 < HN) { src = H; off = e0; }
  else {
    size_t t = e0 - HN; int a = (int)(t >> 22);
    src = (a == 0) ? W0 : (a == 1) ? W1 : (a == 2) ? W2 : W3;
    off = t & (WN - 1);
  }
  fvec4 v0 = *(const fvec4*)(src + off);
  fvec4 v1 = *(const fvec4*)(src + off + 4);
  short8 o;
  o[0] = (short)f2bf(v0[0]); o[1] = (short)f2bf(v0[1]);
  o[2] = (short)f2bf(v0[2]); o[3] = (short)f2bf(v0[3]);
  o[4] = (short)f2bf(v1[0]); o[5] = (short)f2bf(v1[1]);
  o[6] = (short)f2bf(v1[2]); o[7] = (short)f2bf(v1[3]);
  *(short8*)(dst + e0) = o;
}

// ---------------------------------------------------------------------------
// 2) RoPE tables
// ---------------------------------------------------------------------------
__global__ void __launch_bounds__(256) rope_tab_kernel(float* __restrict__ cosT,
                                                       float* __restrict__ sinT)
{
  int idx = blockIdx.x * 256 + threadIdx.x;   // S*32 = 65536
  int t = idx >> 5, fi = idx & 31;
  float inv = powf(10000.0f, -(float)fi * (1.0f / 32.0f));
  float ang = (float)t * inv;
  cosT[idx] = cosf(ang);
  sinT[idx] = sinf(ang);
}

// ---------------------------------------------------------------------------
// 3) Pipelined bf16 GEMM (R8 structure, unchanged): BM=256 BN=128 BK=64,
//    3-deep LDS ring, distance-2 prefetch, counted vmcnt(6), 2 phases x
//    16-MFMA clusters.
// ---------------------------------------------------------------------------
template<int EPI, int NBX>
__global__ void __launch_bounds__(512, 2) gemm8(
    const unsigned short* __restrict__ A,
    const unsigned short* __restrict__ Bw,
    void* __restrict__ dq, void* __restrict__ dk, void* __restrict__ dv)
{
  __shared__ __align__(16) unsigned short Al[3][256 * 64];
  __shared__ __align__(16) unsigned short Bl[3][128 * 64];
  const int tid = threadIdx.x, lane = tid & 63, w = tid >> 6;
  const int wm = w >> 1, wn = w & 1;
  const int ln15 = lane & 15, lq = lane >> 4;

  const int xcd = blockIdx.x & 7, idx = blockIdx.x >> 3;
  const int by = xcd * 2 + idx / NBX, bx = idx % NBX;
  const int m0 = by * 256, n0 = bx * 128;

  const int srow = tid >> 3;                 // 0..63
  const int sc = (tid & 7) ^ (srow & 7);
  const unsigned short* asrc[4];
  const unsigned short* bsrc[2];
#pragma unroll
  for (int l = 0; l < 4; ++l) asrc[l] = A  + (size_t)(m0 + l * 64 + srow) * KC + sc * 8;
#pragma unroll
  for (int l = 0; l < 2; ++l) bsrc[l] = Bw + (size_t)(n0 + l * 64 + srow) * KC + sc * 8;

  const int x7 = ln15 & 7;
  const int slA0 = (lq ^ x7) * 8;
  const int slA1 = ((4 + lq) ^ x7) * 8;
  int rA[4], rB[4];
#pragma unroll
  for (int i = 0; i < 4; ++i) rA[i] = (wm * 64 + i * 16 + ln15) * 64;
#pragma unroll
  for (int j = 0; j < 4; ++j) rB[j] = (wn * 64 + j * 16 + ln15) * 64;

  constexpr int NT = KC / 64;   // 32
  auto stA = [&](int kt, int buf, int l) {
    gload_lds16(asrc[l] + (size_t)kt * 64, &Al[buf][(size_t)(l * 512 + w * 64) * 8]);
  };
  auto stB = [&](int kt, int buf, int l) {
    gload_lds16(bsrc[l] + (size_t)kt * 64, &Bl[buf][(size_t)(l * 512 + w * 64) * 8]);
  };

  stA(0, 0, 0); stA(0, 0, 1); stA(0, 0, 2); stA(0, 0, 3); stB(0, 0, 0); stB(0, 0, 1);
  stA(1, 1, 0); stA(1, 1, 1); stA(1, 1, 2); stA(1, 1, 3); stB(1, 1, 0); stB(1, 1, 1);
  WAITV6; BARX;

  f32x4 acc[4][4] = {};
  int cb = 0, nb = 2;
  for (int kt = 0; kt < NT; ++kt) {
    const unsigned short* Ac = &Al[cb][0];
    const unsigned short* Bc = &Bl[cb][0];
    const bool pf = (kt + 2 < NT);
    short8 a01[2][2], a23[2][2], bf[4][2];

#pragma unroll
    for (int i = 0; i < 2; ++i) {
      a01[i][0] = *(const short8*)&Ac[rA[i] + slA0];
      a01[i][1] = *(const short8*)&Ac[rA[i] + slA1];
    }
#pragma unroll
    for (int j = 0; j < 4; ++j) {
      bf[j][0] = *(const short8*)&Bc[rB[j] + slA0];
      bf[j][1] = *(const short8*)&Bc[rB[j] + slA1];
    }
    if (pf) { stA(kt + 2, nb, 0); stA(kt + 2, nb, 1); stA(kt + 2, nb, 2); }
    BARX;
    WAITL0; SCHED0;
    __builtin_amdgcn_s_setprio(1);
#pragma unroll
    for (int i = 0; i < 2; ++i)
#pragma unroll
      for (int j = 0; j < 4; ++j)
#pragma unroll
        for (int k = 0; k < 2; ++k)
          acc[i][j] = __builtin_amdgcn_mfma_f32_16x16x32_bf16(a01[i][k], bf[j][k], acc[i][j], 0, 0, 0);
    __builtin_amdgcn_s_setprio(0);
    BARX;

#pragma unroll
    for (int i = 0; i < 2; ++i) {
      a23[i][0] = *(const short8*)&Ac[rA[2 + i] + slA0];
      a23[i][1] = *(const short8*)&Ac[rA[2 + i] + slA1];
    }
    if (pf) { stA(kt + 2, nb, 3); stB(kt + 2, nb, 0); stB(kt + 2, nb, 1); }
    BARX;
    WAITL0; SCHED0;
    __builtin_amdgcn_s_setprio(1);
#pragma unroll
    for (int i = 0; i < 2; ++i)
#pragma unroll
      for (int j = 0; j < 4; ++j)
#pragma unroll
        for (int k = 0; k < 2; ++k)
          acc[2 + i][j] = __builtin_amdgcn_mfma_f32_16x16x32_bf16(a23[i][k], bf[j][k], acc[2 + i][j], 0, 0, 0);
    __builtin_amdgcn_s_setprio(0);
    if (kt < NT - 2) { WAITV6; }
    else if (kt == NT - 2) { WAITV0; }
    BARX;

    cb = (cb == 2) ? 0 : cb + 1;
    nb = (nb == 2) ? 0 : nb + 1;
  }

  if (EPI == 0) {
#pragma unroll
    for (int i = 0; i < 4; ++i)
#pragma unroll
      for (int j = 0; j < 4; ++j) {
        int colb = n0 + wn * 64 + j * 16;         // + ln15
        int z = colb >> 11;
        int c2 = (colb & 2047) + ln15;
        int h = c2 >> 7, d = c2 & 127;
        int m = m0 + wm * 64 + i * 16 + lq * 4;   // + rr
        int b = m >> 11, s = m & 2047;
        if (z == 2) {
          us4 pk;
#pragma unroll
          for (int r = 0; r < 4; ++r) pk[r] = f2bf(acc[i][j][r]);
          *(us4*)((unsigned short*)dv + (((size_t)b * NHc + h) * HDc + d) * SS + s) = pk;
        } else {
          unsigned short* D = (unsigned short*)(z ? dk : dq);
#pragma unroll
          for (int r = 0; r < 4; ++r)
            D[(((size_t)b * NHc + h) * SS + s + r) * HDc + d] = f2bf(acc[i][j][r]);
        }
      }
  } else {
    float* O = (float*)dq;
#pragma unroll
    for (int i = 0; i < 4; ++i)
#pragma unroll
      for (int j = 0; j < 4; ++j) {
        int col = n0 + wn * 64 + j * 16 + ln15;
        int m = m0 + wm * 64 + i * 16 + lq * 4;
#pragma unroll
        for (int r = 0; r < 4; ++r)
          O[(size_t)(m + r) * HIDc + col] = acc[i][j][r];
      }
  }
}

// ---------------------------------------------------------------------------
// 4) in-place interleaved RoPE on Q and K
// ---------------------------------------------------------------------------
__global__ void __launch_bounds__(256) rope_kernel(
    unsigned int* __restrict__ Q, unsigned int* __restrict__ Kd,
    const float* __restrict__ cosT, const float* __restrict__ sinT)
{
  constexpr size_t NP = (size_t)BB * NHc * SS * 64;   // pairs per tensor
  size_t gid = (size_t)blockIdx.x * 256 + threadIdx.x;
  unsigned int* P = (gid < NP) ? Q : Kd;
  size_t r = (gid < NP) ? gid : gid - NP;
  int j  = (int)(r & 63);
  int s  = (int)((r >> 6) & (SS - 1));
  int fi = j & 31;
  float c  = cosT[s * 32 + fi];
  float sn = sinT[s * 32 + fi];
  unsigned v = P[r];
  float x1 = bf2f((unsigned short)(v & 0xffff));
  float x2 = bf2f((unsigned short)(v >> 16));
  float y1 = x1 * c - x2 * sn;
  float y2 = x1 * sn + x2 * c;
  P[r] = (unsigned)f2bf(y1) | ((unsigned)f2bf(y2) << 16);
}

// ---------------------------------------------------------------------------
// 5) causal flash attention v7 — swapped-QK 32x32 + split-K work stealing.
//    w2,w3: q-tile 31-t, kv tiles 0..15 (16 tiles, never masked).
//    w0,w1: q-tile t, kv 0..t (diag at t) -> write out, switch to q-tile
//    31-t, kv 16..31-t (diag at 31-t). 17/17/16/16 tiles per wave.
//    Final flash-merge of the two partial (m,l,O) states via LDS.
//    P-writes packed as b64 (throughput-optimal).
// ---------------------------------------------------------------------------
__global__ void __launch_bounds__(256) attn_kernel(
    const unsigned short* __restrict__ Qg,
    const unsigned short* __restrict__ Kg,
    const unsigned short* __restrict__ Vg,   // [b][h][d][s]
    unsigned short* __restrict__ Og)
{
  __shared__ __align__(16) unsigned short Klds[2][64 * 128];   // [kv][d] swizzled
  __shared__ __align__(16) unsigned short Vlds[2][128 * 64];   // [d][kv] swizzled
  __shared__ __align__(16) unsigned short Plds[4][32 * 64];    // per-wave [q][kv] swizzled
  const int tid = threadIdx.x, lane = tid & 63, w = tid >> 6;
  const int l31 = lane & 31, hi = lane >> 5;

  // XCD-aware decode: 512 blocks -> (t 0..15, bh 0..31) with bh%8 == wg%8
  const int wg = blockIdx.x;
  const int xcd = wg & 7, idx = wg >> 3;
  const int bh = xcd + 8 * (idx & 3);
  const int t  = idx >> 2;                   // 0..15 (pair id)

  const int sub1 = w & 1;
  const int q0A = t * 64 + sub1 * 32;        // waves 0,1 phase-A rows
  const int q0M = (31 - t) * 64 + sub1 * 32; // merged tile rows
  const int ntiles = 32 - t;

  const size_t hbase = (size_t)bh * SS * HDc;
  const float CE = 1.44269504089f * 0.08838834764831845f;  // log2(e)/sqrt(128)
  const int b = bh >> 4, h = bh & 15;

  // initial Q rows: w0,w1 -> tile t; w2,w3 -> tile 31-t
  short8 qf[8];
  {
    int q0 = (w < 2) ? q0A : q0M;
#pragma unroll
    for (int ks = 0; ks < 8; ++ks)
      qf[ks] = *(const short8*)(Qg + hbase + (size_t)(q0 + l31) * HDc + ks * 16 + hi * 8);
  }

  f32x16 accO[4];
#pragma unroll
  for (int db = 0; db < 4; ++db)
#pragma unroll
    for (int r = 0; r < 16; ++r) accO[db][r] = 0.f;
  float mr = -1e30f, lr = 0.f;

  auto stage = [&](int kvt, int buf) {
    const int kv0 = kvt * 64;
#pragma unroll
    for (int p = 0; p < 4; ++p) {
      int c = p * 256 + w * 64 + lane;
      int krow = c >> 4, ksl = c & 15;
      gload_lds16(Kg + hbase + (size_t)(kv0 + krow) * HDc + ((ksl ^ (krow & 7)) << 3),
                  (unsigned short*)&Klds[buf][0] + (size_t)(p * 256 + w * 64) * 8);
      int vd = c >> 3, vsl = c & 7;
      gload_lds16(Vg + hbase + (size_t)vd * SS + kv0 + ((vsl ^ (vd & 7)) << 3),
                  (unsigned short*)&Vlds[buf][0] + (size_t)(p * 256 + w * 64) * 8);
    }
  };

  stage(0, 0);
  __syncthreads();
  int cur = 0;
  for (int kvt = 0; kvt < ntiles; ++kvt) {
    if (kvt + 1 < ntiles) stage(kvt + 1, cur ^ 1);

    bool active, diag;
    if (w < 2) {
      active = (kvt <= t) || (kvt >= 16 && kvt <= 31 - t);
      diag = (kvt == t) || (kvt == 31 - t);
    } else { active = (kvt <= 15); diag = false; }

    if (active) {
      const bool haveT1 = (!diag) || sub1;

      // ---- swapped QK^T: D[k][q] ----
      f32x16 s0, s1;
#pragma unroll
      for (int r = 0; r < 16; ++r) s0[r] = 0.f;
      __builtin_amdgcn_s_setprio(1);
#pragma unroll
      for (int ks = 0; ks < 8; ++ks) {
        int row = l31;
        short8 kf = *(const short8*)&Klds[cur][row * 128 + (((2 * ks + hi) ^ (row & 7)) << 3)];
        s0 = __builtin_amdgcn_mfma_f32_32x32x16_bf16(kf, qf[ks], s0, 0, 0, 0);
      }
      if (haveT1) {
#pragma unroll
        for (int r = 0; r < 16; ++r) s1[r] = 0.f;
#pragma unroll
        for (int ks = 0; ks < 8; ++ks) {
          int row = 32 + l31;
          short8 kf = *(const short8*)&Klds[cur][row * 128 + (((2 * ks + hi) ^ (row & 7)) << 3)];
          s1 = __builtin_amdgcn_mfma_f32_32x32x16_bf16(kf, qf[ks], s1, 0, 0, 0);
        }
      }
      __builtin_amdgcn_s_setprio(0);

      if (diag) {                            // mask rowid > own q within 32-block
        if (sub1) {
#pragma unroll
          for (int r = 0; r < 16; ++r)
            if (((r & 3) + 8 * (r >> 2) + 4 * hi) > l31) s1[r] = -1e30f;
        } else {
#pragma unroll
          for (int r = 0; r < 16; ++r)
            if (((r & 3) + 8 * (r >> 2) + 4 * hi) > l31) s0[r] = -1e30f;
        }
      }

      // ---- in-register online softmax ----
      float pmax = s0[0];
#pragma unroll
      for (int r = 1; r < 16; ++r) pmax = fmaxf(pmax, s0[r]);
      if (haveT1) {
#pragma unroll
        for (int r = 0; r < 16; ++r) pmax = fmaxf(pmax, s1[r]);
      }
      pmax = fmaxf(pmax, __shfl_xor(pmax, 32));

      int grow = (CE * (pmax - mr) > 8.0f) ? 1 : 0;
      if (__any(grow)) {
        float mn = fmaxf(mr, pmax);
        float al = exp2f(CE * (mr - mn));
        mr = mn; lr *= al;
        float alr[16];
#pragma unroll
        for (int r = 0; r < 16; ++r)
          alr[r] = __shfl(al, (r & 3) + 8 * (r >> 2) + 4 * hi);
#pragma unroll
        for (int db = 0; db < 4; ++db)
#pragma unroll
          for (int r = 0; r < 16; ++r) accO[db][r] *= alr[r];
      }

      float psum = 0.f;
#pragma unroll
      for (int r = 0; r < 16; ++r) {
        float p = exp2f(CE * (s0[r] - mr));
        s0[r] = p; psum += p;
      }
      if (haveT1) {
#pragma unroll
        for (int r = 0; r < 16; ++r) {
          float p = exp2f(CE * (s1[r] - mr));
          s1[r] = p; psum += p;
        }
      }
      psum += __shfl_xor(psum, 32);
      lr += psum;

      // ---- P -> per-wave LDS, b64-packed (regs 4i..4i+3 are kv-consecutive) ----
#pragma unroll
      for (int i = 0; i < 4; ++i) {
        uint2v pk;
        pk[0] = cvtpk_bf16(s0[4 * i], s0[4 * i + 1]);
        pk[1] = cvtpk_bf16(s0[4 * i + 2], s0[4 * i + 3]);
        int chunk = i ^ (l31 & 7);
        *(uint2v*)&Plds[w][l31 * 64 + chunk * 8 + hi * 4] = pk;
      }
      if (haveT1) {
#pragma unroll
        for (int i = 0; i < 4; ++i) {
          uint2v pk;
          pk[0] = cvtpk_bf16(s1[4 * i], s1[4 * i + 1]);
          pk[1] = cvtpk_bf16(s1[4 * i + 2], s1[4 * i + 3]);
          int chunk = (4 + i) ^ (l31 & 7);
          *(uint2v*)&Plds[w][l31 * 64 + chunk * 8 + hi * 4] = pk;
        }
      }

      // ---- PV ----
      short8 ap[4];
#pragma unroll
      for (int ks = 0; ks < 2; ++ks)
        ap[ks] = *(const short8*)&Plds[w][l31 * 64 + (((2 * ks + hi) ^ (l31 & 7)) << 3)];
      if (haveT1) {
#pragma unroll
        for (int ks = 2; ks < 4; ++ks)
          ap[ks] = *(const short8*)&Plds[w][l31 * 64 + (((2 * ks + hi) ^ (l31 & 7)) << 3)];
      }

      __builtin_amdgcn_s_setprio(1);
#pragma unroll
      for (int db = 0; db < 4; ++db) {
        int row = db * 32 + l31;
#pragma unroll
        for (int ks = 0; ks < 2; ++ks) {
          short8 vf = *(const short8*)&Vlds[cur][row * 64 + (((2 * ks + hi) ^ (row & 7)) << 3)];
          accO[db] = __builtin_amdgcn_mfma_f32_32x32x16_bf16(ap[ks], vf, accO[db], 0, 0, 0);
        }
      }
      if (haveT1) {
#pragma unroll
        for (int db = 0; db < 4; ++db) {
          int row = db * 32 + l31;
#pragma unroll
          for (int ks = 2; ks < 4; ++ks) {
            short8 vf = *(const short8*)&Vlds[cur][row * 64 + (((2 * ks + hi) ^ (row & 7)) << 3)];
            accO[db] = __builtin_amdgcn_mfma_f32_32x32x16_bf16(ap[ks], vf, accO[db], 0, 0, 0);
          }
        }
      }
      __builtin_amdgcn_s_setprio(0);
    }

    // ---- waves 0,1: finish tile t, switch to stolen tail of tile 31-t ----
    if (w < 2 && kvt == t) {
      float il = 1.0f / lr;
      float ilr[16];
#pragma unroll
      for (int r = 0; r < 16; ++r)
        ilr[r] = __shfl(il, (r & 3) + 8 * (r >> 2) + 4 * hi);
#pragma unroll
      for (int db = 0; db < 4; ++db)
#pragma unroll
        for (int r = 0; r < 16; ++r) {
          int q = q0A + (r & 3) + 8 * (r >> 2) + 4 * hi;
          int d = db * 32 + l31;
          Og[((size_t)b * SS + q) * HIDc + h * HDc + d] = f2bf(accO[db][r] * ilr[r]);
        }
#pragma unroll
      for (int ks = 0; ks < 8; ++ks)
        qf[ks] = *(const short8*)(Qg + hbase + (size_t)(q0M + l31) * HDc + ks * 16 + hi * 8);
#pragma unroll
      for (int db = 0; db < 4; ++db)
#pragma unroll
        for (int r = 0; r < 16; ++r) accO[db][r] = 0.f;
      mr = -1e30f; lr = 0.f;
    }

    __syncthreads();
    cur ^= 1;
  }

  // ---- flash-merge of the split-K halves of tile 31-t ----
  // waves 2,3 dump (accO, m, l) into Klds/Vlds space; waves 0,1 merge.
  float* accL = (float*)&Klds[0][0];   // 32 KB: [w-2][lane][64] chunk-swizzled
  float* mlL  = (float*)&Vlds[0][0];   // [w-2][2][64]
  if (w >= 2) {
    int base = (w - 2) * 4096 + lane * 64;
#pragma unroll
    for (int db = 0; db < 4; ++db)
#pragma unroll
      for (int g = 0; g < 4; ++g) {
        int chunk = (db * 4 + g) ^ (lane & 7);
        f32x4 v = { accO[db][4 * g], accO[db][4 * g + 1], accO[db][4 * g + 2], accO[db][4 * g + 3] };
        *(f32x4*)&accL[base + chunk * 4] = v;
      }
    mlL[(w - 2) * 128 + lane] = mr;
    mlL[(w - 2) * 128 + 64 + lane] = lr;
  }
  __syncthreads();
  if (w < 2) {
    int base = w * 4096 + lane * 64;
    float m2 = mlL[w * 128 + lane];
    float l2 = mlL[w * 128 + 64 + lane];
    float M  = fmaxf(mr, m2);
    float a0 = exp2f(CE * (mr - M));
    float a2 = exp2f(CE * (m2 - M));
    float il = 1.0f / (lr * a0 + l2 * a2);
    float g0[16], g2[16];
#pragma unroll
    for (int r = 0; r < 16; ++r) {
      int cr = (r & 3) + 8 * (r >> 2) + 4 * hi;
      g0[r] = __shfl(a0 * il, cr);
      g2[r] = __shfl(a2 * il, cr);
    }
#pragma unroll
    for (int db = 0; db < 4; ++db)
#pragma unroll
      for (int g = 0; g < 4; ++g) {
        int chunk = (db * 4 + g) ^ (lane & 7);
        f32x4 pv = *(const f32x4*)&accL[base + chunk * 4];
#pragma unroll
        for (int e = 0; e < 4; ++e) {
          int r = 4 * g + e;
          float v = accO[db][r] * g0[r] + pv[e] * g2[r];
          int q = q0M + (r & 3) + 8 * (r >> 2) + 4 * hi;
          int d = db * 32 + l31;
          Og[((size_t)b * SS + q) * HIDc + h * HDc + d] = f2bf(v);
        }
      }
  }
}

// ---------------------------------------------------------------------------
extern "C" void kernel_launch(void* const* d_in, const int* in_sizes, int n_in,
                              void* d_out, int out_size, void* d_ws, size_t ws_size,
                              hipStream_t stream)
{
  if (ws_size < WS_NEED) return;

  const float* H  = (const float*)d_in[0];
  const float* Wq = (const float*)d_in[1];
  const float* Wk = (const float*)d_in[2];
  const float* Wv = (const float*)d_in[3];
  const float* Wo = (const float*)d_in[4];
  char* ws = (char*)d_ws;
  unsigned short* HB = (unsigned short*)(ws + OFF_HB);
  unsigned short* WB = (unsigned short*)(ws + OFF_WB);
  unsigned short* Qb = (unsigned short*)(ws + OFF_Q);
  unsigned short* Kb = (unsigned short*)(ws + OFF_K);
  unsigned short* Vb = (unsigned short*)(ws + OFF_V);
  unsigned short* AT = (unsigned short*)(ws + OFF_ATT);
  float* cosT = (float*)(ws + OFF_COS);
  float* sinT = (float*)(ws + OFF_SIN);

  cvt_kernel<<<12288, 256, 0, stream>>>(H, Wq, Wk, Wv, Wo, HB);
  rope_tab_kernel<<<256, 256, 0, stream>>>(cosT, sinT);
  gemm8<0, 48><<<768, 512, 0, stream>>>(HB, WB, Qb, Kb, Vb);
  rope_kernel<<<32768, 256, 0, stream>>>((unsigned*)Qb, (unsigned*)Kb, cosT, sinT);
  attn_kernel<<<512, 256, 0, stream>>>(Qb, Kb, Vb, AT);
  gemm8<1, 16><<<256, 512, 0, stream>>>(AT, WB + (size_t)3 * HIDc * KC,
                                        d_out, nullptr, nullptr);
}

// Round 10
// 273.507 us; speedup vs baseline: 1.1991x; 1.1991x over previous
//
#include <hip/hip_runtime.h>
#include <math.h>

typedef __attribute__((ext_vector_type(8))) short short8;
typedef __attribute__((ext_vector_type(4))) float f32x4;
typedef __attribute__((ext_vector_type(16))) float f32x16;
typedef __attribute__((ext_vector_type(4))) float fvec4;
typedef __attribute__((ext_vector_type(4))) unsigned short us4;
typedef __attribute__((ext_vector_type(2))) unsigned int uint2v;

#define DI __device__ __forceinline__
#define BARX asm volatile("s_barrier" ::: "memory")
#define WAITV6 asm volatile("s_waitcnt vmcnt(6)" ::: "memory")
#define WAITV0 asm volatile("s_waitcnt vmcnt(0)" ::: "memory")
#define WAITL0 asm volatile("s_waitcnt lgkmcnt(0)" ::: "memory")
#define SCHED0 __builtin_amdgcn_sched_barrier(0)

constexpr int BB = 2, SS = 2048, HIDc = 2048, NHc = 16, HDc = 128;
constexpr int MT = BB * SS;     // 4096 tokens
constexpr int KC = HIDc;        // 2048 inner dim

// ---- workspace layout (bytes) ----
constexpr size_t OFF_HB  = 0;                                      // H bf16   [4096][2048]
constexpr size_t OFF_WB  = OFF_HB + (size_t)MT * KC * 2;           // W bf16   4x[2048][2048]
constexpr size_t OFF_Q   = OFF_WB + (size_t)4 * HIDc * KC * 2;     // Q bf16   [b][h][s][d]
constexpr size_t OFF_K   = OFF_Q  + (size_t)BB * NHc * SS * HDc * 2;
constexpr size_t OFF_V   = OFF_K  + (size_t)BB * NHc * SS * HDc * 2; // V bf16 [b][h][d][s]
constexpr size_t OFF_ATT = OFF_V  + (size_t)BB * NHc * SS * HDc * 2; // attn bf16 [b*s][hid]
constexpr size_t OFF_COS = OFF_ATT + (size_t)MT * HIDc * 2;
constexpr size_t OFF_SIN = OFF_COS + (size_t)SS * 32 * 4;
constexpr size_t WS_NEED = OFF_SIN + (size_t)SS * 32 * 4;          // ~118 MB

DI float bf2f(unsigned short u) { union { unsigned u; float f; } v; v.u = (unsigned)u << 16; return v.f; }
DI unsigned short f2bf(float f) {
  union { float f; unsigned u; } v; v.f = f;
  unsigned r = v.u + 0x7fffu + ((v.u >> 16) & 1u);
  return (unsigned short)(r >> 16);
}

DI void gload_lds16(const void* g, void* l) {
  __builtin_amdgcn_global_load_lds((const __attribute__((address_space(1))) void*)g,
                                   (__attribute__((address_space(3))) void*)l, 16, 0, 0);
}

DI unsigned cvtpk_bf16(float lo, float hi_) {
  unsigned r;
  asm("v_cvt_pk_bf16_f32 %0, %1, %2" : "=v"(r) : "v"(lo), "v"(hi_));
  return r;
}

// ---------------------------------------------------------------------------
// 1) fp32 -> bf16 convert of H and the 4 weights into one contiguous region
// ---------------------------------------------------------------------------
__global__ void __launch_bounds__(256) cvt_kernel(
    const float* __restrict__ H,  const float* __restrict__ W0,
    const float* __restrict__ W1, const float* __restrict__ W2,
    const float* __restrict__ W3, unsigned short* __restrict__ dst)
{
  constexpr size_t HN = (size_t)MT * KC;      // 8388608
  constexpr size_t WN = (size_t)HIDc * KC;    // 4194304 = 2^22
  size_t e0 = ((size_t)blockIdx.x * 256 + threadIdx.x) * 8;
  const float* src; size_t off;
  if (e0 < HN) { src = H; off = e0; }
  else {
    size_t t = e0 - HN; int a = (int)(t >> 22);
    src = (a == 0) ? W0 : (a == 1) ? W1 : (a == 2) ? W2 : W3;
    off = t & (WN - 1);
  }
  fvec4 v0 = *(const fvec4*)(src + off);
  fvec4 v1 = *(const fvec4*)(src + off + 4);
  short8 o;
  o[0] = (short)f2bf(v0[0]); o[1] = (short)f2bf(v0[1]);
  o[2] = (short)f2bf(v0[2]); o[3] = (short)f2bf(v0[3]);
  o[4] = (short)f2bf(v1[0]); o[5] = (short)f2bf(v1[1]);
  o[6] = (short)f2bf(v1[2]); o[7] = (short)f2bf(v1[3]);
  *(short8*)(dst + e0) = o;
}

// ---------------------------------------------------------------------------
// 2) RoPE tables
// ---------------------------------------------------------------------------
__global__ void __launch_bounds__(256) rope_tab_kernel(float* __restrict__ cosT,
                                                       float* __restrict__ sinT)
{
  int idx = blockIdx.x * 256 + threadIdx.x;   // S*32 = 65536
  int t = idx >> 5, fi = idx & 31;
  float inv = powf(10000.0f, -(float)fi * (1.0f / 32.0f));
  float ang = (float)t * inv;
  cosT[idx] = cosf(ang);
  sinT[idx] = sinf(ang);
}

// ---------------------------------------------------------------------------
// 3) Pipelined bf16 GEMM (R8 structure, unchanged): BM=256 BN=128 BK=64,
//    3-deep LDS ring, distance-2 prefetch, counted vmcnt(6), 2 phases x
//    16-MFMA clusters.
// ---------------------------------------------------------------------------
template<int EPI, int NBX>
__global__ void __launch_bounds__(512, 2) gemm8(
    const unsigned short* __restrict__ A,
    const unsigned short* __restrict__ Bw,
    void* __restrict__ dq, void* __restrict__ dk, void* __restrict__ dv)
{
  __shared__ __align__(16) unsigned short Al[3][256 * 64];
  __shared__ __align__(16) unsigned short Bl[3][128 * 64];
  const int tid = threadIdx.x, lane = tid & 63, w = tid >> 6;
  const int wm = w >> 1, wn = w & 1;
  const int ln15 = lane & 15, lq = lane >> 4;

  const int xcd = blockIdx.x & 7, idx = blockIdx.x >> 3;
  const int by = xcd * 2 + idx / NBX, bx = idx % NBX;
  const int m0 = by * 256, n0 = bx * 128;

  const int srow = tid >> 3;                 // 0..63
  const int sc = (tid & 7) ^ (srow & 7);
  const unsigned short* asrc[4];
  const unsigned short* bsrc[2];
#pragma unroll
  for (int l = 0; l < 4; ++l) asrc[l] = A  + (size_t)(m0 + l * 64 + srow) * KC + sc * 8;
#pragma unroll
  for (int l = 0; l < 2; ++l) bsrc[l] = Bw + (size_t)(n0 + l * 64 + srow) * KC + sc * 8;

  const int x7 = ln15 & 7;
  const int slA0 = (lq ^ x7) * 8;
  const int slA1 = ((4 + lq) ^ x7) * 8;
  int rA[4], rB[4];
#pragma unroll
  for (int i = 0; i < 4; ++i) rA[i] = (wm * 64 + i * 16 + ln15) * 64;
#pragma unroll
  for (int j = 0; j < 4; ++j) rB[j] = (wn * 64 + j * 16 + ln15) * 64;

  constexpr int NT = KC / 64;   // 32
  auto stA = [&](int kt, int buf, int l) {
    gload_lds16(asrc[l] + (size_t)kt * 64, &Al[buf][(size_t)(l * 512 + w * 64) * 8]);
  };
  auto stB = [&](int kt, int buf, int l) {
    gload_lds16(bsrc[l] + (size_t)kt * 64, &Bl[buf][(size_t)(l * 512 + w * 64) * 8]);
  };

  stA(0, 0, 0); stA(0, 0, 1); stA(0, 0, 2); stA(0, 0, 3); stB(0, 0, 0); stB(0, 0, 1);
  stA(1, 1, 0); stA(1, 1, 1); stA(1, 1, 2); stA(1, 1, 3); stB(1, 1, 0); stB(1, 1, 1);
  WAITV6; BARX;

  f32x4 acc[4][4] = {};
  int cb = 0, nb = 2;
  for (int kt = 0; kt < NT; ++kt) {
    const unsigned short* Ac = &Al[cb][0];
    const unsigned short* Bc = &Bl[cb][0];
    const bool pf = (kt + 2 < NT);
    short8 a01[2][2], a23[2][2], bf[4][2];

#pragma unroll
    for (int i = 0; i < 2; ++i) {
      a01[i][0] = *(const short8*)&Ac[rA[i] + slA0];
      a01[i][1] = *(const short8*)&Ac[rA[i] + slA1];
    }
#pragma unroll
    for (int j = 0; j < 4; ++j) {
      bf[j][0] = *(const short8*)&Bc[rB[j] + slA0];
      bf[j][1] = *(const short8*)&Bc[rB[j] + slA1];
    }
    if (pf) { stA(kt + 2, nb, 0); stA(kt + 2, nb, 1); stA(kt + 2, nb, 2); }
    BARX;
    WAITL0; SCHED0;
    __builtin_amdgcn_s_setprio(1);
#pragma unroll
    for (int i = 0; i < 2; ++i)
#pragma unroll
      for (int j = 0; j < 4; ++j)
#pragma unroll
        for (int k = 0; k < 2; ++k)
          acc[i][j] = __builtin_amdgcn_mfma_f32_16x16x32_bf16(a01[i][k], bf[j][k], acc[i][j], 0, 0, 0);
    __builtin_amdgcn_s_setprio(0);
    BARX;

#pragma unroll
    for (int i = 0; i < 2; ++i) {
      a23[i][0] = *(const short8*)&Ac[rA[2 + i] + slA0];
      a23[i][1] = *(const short8*)&Ac[rA[2 + i] + slA1];
    }
    if (pf) { stA(kt + 2, nb, 3); stB(kt + 2, nb, 0); stB(kt + 2, nb, 1); }
    BARX;
    WAITL0; SCHED0;
    __builtin_amdgcn_s_setprio(1);
#pragma unroll
    for (int i = 0; i < 2; ++i)
#pragma unroll
      for (int j = 0; j < 4; ++j)
#pragma unroll
        for (int k = 0; k < 2; ++k)
          acc[2 + i][j] = __builtin_amdgcn_mfma_f32_16x16x32_bf16(a23[i][k], bf[j][k], acc[2 + i][j], 0, 0, 0);
    __builtin_amdgcn_s_setprio(0);
    if (kt < NT - 2) { WAITV6; }
    else if (kt == NT - 2) { WAITV0; }
    BARX;

    cb = (cb == 2) ? 0 : cb + 1;
    nb = (nb == 2) ? 0 : nb + 1;
  }

  if (EPI == 0) {
#pragma unroll
    for (int i = 0; i < 4; ++i)
#pragma unroll
      for (int j = 0; j < 4; ++j) {
        int colb = n0 + wn * 64 + j * 16;         // + ln15
        int z = colb >> 11;
        int c2 = (colb & 2047) + ln15;
        int h = c2 >> 7, d = c2 & 127;
        int m = m0 + wm * 64 + i * 16 + lq * 4;   // + rr
        int b = m >> 11, s = m & 2047;
        if (z == 2) {
          us4 pk;
#pragma unroll
          for (int r = 0; r < 4; ++r) pk[r] = f2bf(acc[i][j][r]);
          *(us4*)((unsigned short*)dv + (((size_t)b * NHc + h) * HDc + d) * SS + s) = pk;
        } else {
          unsigned short* D = (unsigned short*)(z ? dk : dq);
#pragma unroll
          for (int r = 0; r < 4; ++r)
            D[(((size_t)b * NHc + h) * SS + s + r) * HDc + d] = f2bf(acc[i][j][r]);
        }
      }
  } else {
    float* O = (float*)dq;
#pragma unroll
    for (int i = 0; i < 4; ++i)
#pragma unroll
      for (int j = 0; j < 4; ++j) {
        int col = n0 + wn * 64 + j * 16 + ln15;
        int m = m0 + wm * 64 + i * 16 + lq * 4;
#pragma unroll
        for (int r = 0; r < 4; ++r)
          O[(size_t)(m + r) * HIDc + col] = acc[i][j][r];
      }
  }
}

// ---------------------------------------------------------------------------
// 4) in-place interleaved RoPE on Q and K
// ---------------------------------------------------------------------------
__global__ void __launch_bounds__(256) rope_kernel(
    unsigned int* __restrict__ Q, unsigned int* __restrict__ Kd,
    const float* __restrict__ cosT, const float* __restrict__ sinT)
{
  constexpr size_t NP = (size_t)BB * NHc * SS * 64;   // pairs per tensor
  size_t gid = (size_t)blockIdx.x * 256 + threadIdx.x;
  unsigned int* P = (gid < NP) ? Q : Kd;
  size_t r = (gid < NP) ? gid : gid - NP;
  int j  = (int)(r & 63);
  int s  = (int)((r >> 6) & (SS - 1));
  int fi = j & 31;
  float c  = cosT[s * 32 + fi];
  float sn = sinT[s * 32 + fi];
  unsigned v = P[r];
  float x1 = bf2f((unsigned short)(v & 0xffff));
  float x2 = bf2f((unsigned short)(v >> 16));
  float y1 = x1 * c - x2 * sn;
  float y2 = x1 * sn + x2 * c;
  P[r] = (unsigned)f2bf(y1) | ((unsigned)f2bf(y2) << 16);
}

// ---------------------------------------------------------------------------
// 5) causal flash attention v8 — 8-wave blocks, SIMD-complementary pairing.
//    256 blocks (1/CU) x 512 thr. Block owns q-tiles {tt, tt+8, 31-tt, 23-tt}
//    for one bh. Waves: w0,w1->tt; w2,w3->tt+8; w4,w5->31-tt; w6,w7->23-tt.
//    With round-robin wave->SIMD (w%4), each SIMD hosts a complementary pair
//    => exactly 33 wave-tiles per SIMD, uniform across all blocks.
//    Single KV staging stream per CU (2+2 loads/thread/tile).
// ---------------------------------------------------------------------------
__global__ void __launch_bounds__(512, 2) attn_kernel(
    const unsigned short* __restrict__ Qg,
    const unsigned short* __restrict__ Kg,
    const unsigned short* __restrict__ Vg,   // [b][h][d][s]
    unsigned short* __restrict__ Og)
{
  __shared__ __align__(16) unsigned short Klds[2][64 * 128];   // [kv][d] swizzled
  __shared__ __align__(16) unsigned short Vlds[2][128 * 64];   // [d][kv] swizzled
  __shared__ __align__(16) unsigned short Plds[8][32 * 64];    // per-wave [q][kv] swizzled
  const int tid = threadIdx.x, lane = tid & 63, w = tid >> 6;
  const int l31 = lane & 31, hi = lane >> 5;

  // XCD-aware decode: 256 blocks -> (tt 0..7, bh 0..31) with bh%8 == wg%8
  const int wg = blockIdx.x;
  const int xcd = wg & 7, idx = wg >> 3;
  const int bh = xcd + 8 * (idx & 3);
  const int tt = idx >> 2;                   // 0..7

  // SIMD-complementary tile assignment
  const int qtile = (w < 2) ? tt : (w < 4) ? (tt + 8) : (w < 6) ? (31 - tt) : (23 - tt);
  const int sub1 = w & 1;
  const int q0w = qtile * 64 + sub1 * 32;
  const int ntiles = 32 - tt;

  const size_t hbase = (size_t)bh * SS * HDc;
  const float CE = 1.44269504089f * 0.08838834764831845f;  // log2(e)/sqrt(128)
  const int b = bh >> 4, h = bh & 15;

  short8 qf[8];
#pragma unroll
  for (int ks = 0; ks < 8; ++ks)
    qf[ks] = *(const short8*)(Qg + hbase + (size_t)(q0w + l31) * HDc + ks * 16 + hi * 8);

  f32x16 accO[4];
#pragma unroll
  for (int db = 0; db < 4; ++db)
#pragma unroll
    for (int r = 0; r < 16; ++r) accO[db][r] = 0.f;
  float mr = -1e30f, lr = 0.f;

  // 512 threads: 2 K-chunks + 2 V-chunks per thread per tile
  auto stage = [&](int kvt, int buf) {
    const int kv0 = kvt * 64;
#pragma unroll
    for (int p = 0; p < 2; ++p) {
      int c = p * 512 + tid;                 // 0..1023
      int krow = c >> 4, ksl = c & 15;       // K: [kv 64][d 128]
      gload_lds16(Kg + hbase + (size_t)(kv0 + krow) * HDc + ((ksl ^ (krow & 7)) << 3),
                  (unsigned short*)&Klds[buf][0] + (size_t)c * 8);
      int vd = c >> 3, vsl = c & 7;          // V: [d 128][kv 64]
      gload_lds16(Vg + hbase + (size_t)vd * SS + kv0 + ((vsl ^ (vd & 7)) << 3),
                  (unsigned short*)&Vlds[buf][0] + (size_t)c * 8);
    }
  };

  stage(0, 0);
  __syncthreads();
  int cur = 0;
  for (int kvt = 0; kvt < ntiles; ++kvt) {
    if (kvt + 1 < ntiles) stage(kvt + 1, cur ^ 1);

    if (kvt <= qtile) {
      const bool diag = (kvt == qtile);
      const bool haveT1 = (!diag) || sub1;

      // ---- swapped QK^T: D[k][q] ----
      f32x16 s0, s1;
#pragma unroll
      for (int r = 0; r < 16; ++r) s0[r] = 0.f;
      __builtin_amdgcn_s_setprio(1);
#pragma unroll
      for (int ks = 0; ks < 8; ++ks) {
        int row = l31;
        short8 kf = *(const short8*)&Klds[cur][row * 128 + (((2 * ks + hi) ^ (row & 7)) << 3)];
        s0 = __builtin_amdgcn_mfma_f32_32x32x16_bf16(kf, qf[ks], s0, 0, 0, 0);
      }
      if (haveT1) {
#pragma unroll
        for (int r = 0; r < 16; ++r) s1[r] = 0.f;
#pragma unroll
        for (int ks = 0; ks < 8; ++ks) {
          int row = 32 + l31;
          short8 kf = *(const short8*)&Klds[cur][row * 128 + (((2 * ks + hi) ^ (row & 7)) << 3)];
          s1 = __builtin_amdgcn_mfma_f32_32x32x16_bf16(kf, qf[ks], s1, 0, 0, 0);
        }
      }
      __builtin_amdgcn_s_setprio(0);

      if (diag) {                            // mask rowid > own q within 32-block
        if (sub1) {
#pragma unroll
          for (int r = 0; r < 16; ++r)
            if (((r & 3) + 8 * (r >> 2) + 4 * hi) > l31) s1[r] = -1e30f;
        } else {
#pragma unroll
          for (int r = 0; r < 16; ++r)
            if (((r & 3) + 8 * (r >> 2) + 4 * hi) > l31) s0[r] = -1e30f;
        }
      }

      // ---- in-register online softmax ----
      float pmax = s0[0];
#pragma unroll
      for (int r = 1; r < 16; ++r) pmax = fmaxf(pmax, s0[r]);
      if (haveT1) {
#pragma unroll
        for (int r = 0; r < 16; ++r) pmax = fmaxf(pmax, s1[r]);
      }
      pmax = fmaxf(pmax, __shfl_xor(pmax, 32));

      int grow = (CE * (pmax - mr) > 8.0f) ? 1 : 0;
      if (__any(grow)) {
        float mn = fmaxf(mr, pmax);
        float al = exp2f(CE * (mr - mn));
        mr = mn; lr *= al;
        float alr[16];
#pragma unroll
        for (int r = 0; r < 16; ++r)
          alr[r] = __shfl(al, (r & 3) + 8 * (r >> 2) + 4 * hi);
#pragma unroll
        for (int db = 0; db < 4; ++db)
#pragma unroll
          for (int r = 0; r < 16; ++r) accO[db][r] *= alr[r];
      }

      float psum = 0.f;
#pragma unroll
      for (int r = 0; r < 16; ++r) {
        float p = exp2f(CE * (s0[r] - mr));
        s0[r] = p; psum += p;
      }
      if (haveT1) {
#pragma unroll
        for (int r = 0; r < 16; ++r) {
          float p = exp2f(CE * (s1[r] - mr));
          s1[r] = p; psum += p;
        }
      }
      psum += __shfl_xor(psum, 32);
      lr += psum;

      // ---- P -> per-wave LDS, b64-packed (regs 4i..4i+3 kv-consecutive) ----
#pragma unroll
      for (int i = 0; i < 4; ++i) {
        uint2v pk;
        pk[0] = cvtpk_bf16(s0[4 * i], s0[4 * i + 1]);
        pk[1] = cvtpk_bf16(s0[4 * i + 2], s0[4 * i + 3]);
        int chunk = i ^ (l31 & 7);
        *(uint2v*)&Plds[w][l31 * 64 + chunk * 8 + hi * 4] = pk;
      }
      if (haveT1) {
#pragma unroll
        for (int i = 0; i < 4; ++i) {
          uint2v pk;
          pk[0] = cvtpk_bf16(s1[4 * i], s1[4 * i + 1]);
          pk[1] = cvtpk_bf16(s1[4 * i + 2], s1[4 * i + 3]);
          int chunk = (4 + i) ^ (l31 & 7);
          *(uint2v*)&Plds[w][l31 * 64 + chunk * 8 + hi * 4] = pk;
        }
      }

      // ---- PV ----
      short8 ap[4];
#pragma unroll
      for (int ks = 0; ks < 2; ++ks)
        ap[ks] = *(const short8*)&Plds[w][l31 * 64 + (((2 * ks + hi) ^ (l31 & 7)) << 3)];
      if (haveT1) {
#pragma unroll
        for (int ks = 2; ks < 4; ++ks)
          ap[ks] = *(const short8*)&Plds[w][l31 * 64 + (((2 * ks + hi) ^ (l31 & 7)) << 3)];
      }

      __builtin_amdgcn_s_setprio(1);
#pragma unroll
      for (int db = 0; db < 4; ++db) {
        int row = db * 32 + l31;
#pragma unroll
        for (int ks = 0; ks < 2; ++ks) {
          short8 vf = *(const short8*)&Vlds[cur][row * 64 + (((2 * ks + hi) ^ (row & 7)) << 3)];
          accO[db] = __builtin_amdgcn_mfma_f32_32x32x16_bf16(ap[ks], vf, accO[db], 0, 0, 0);
        }
      }
      if (haveT1) {
#pragma unroll
        for (int db = 0; db < 4; ++db) {
          int row = db * 32 + l31;
#pragma unroll
          for (int ks = 2; ks < 4; ++ks) {
            short8 vf = *(const short8*)&Vlds[cur][row * 64 + (((2 * ks + hi) ^ (row & 7)) << 3)];
            accO[db] = __builtin_amdgcn_mfma_f32_32x32x16_bf16(ap[ks], vf, accO[db], 0, 0, 0);
          }
        }
      }
      __builtin_amdgcn_s_setprio(0);
    }

    __syncthreads();   // drains vmcnt -> buf[cur^1] ready
    cur ^= 1;
  }

  // ---- epilogue: O[q][d] = accO / lr ----
  float il = 1.0f / lr;
  float ilr[16];
#pragma unroll
  for (int r = 0; r < 16; ++r)
    ilr[r] = __shfl(il, (r & 3) + 8 * (r >> 2) + 4 * hi);
#pragma unroll
  for (int db = 0; db < 4; ++db)
#pragma unroll
    for (int r = 0; r < 16; ++r) {
      int q = q0w + (r & 3) + 8 * (r >> 2) + 4 * hi;
      int d = db * 32 + l31;
      Og[((size_t)b * SS + q) * HIDc + h * HDc + d] = f2bf(accO[db][r] * ilr[r]);
    }
}

// ---------------------------------------------------------------------------
extern "C" void kernel_launch(void* const* d_in, const int* in_sizes, int n_in,
                              void* d_out, int out_size, void* d_ws, size_t ws_size,
                              hipStream_t stream)
{
  if (ws_size < WS_NEED) return;

  const float* H  = (const float*)d_in[0];
  const float* Wq = (const float*)d_in[1];
  const float* Wk = (const float*)d_in[2];
  const float* Wv = (const float*)d_in[3];
  const float* Wo = (const float*)d_in[4];
  char* ws = (char*)d_ws;
  unsigned short* HB = (unsigned short*)(ws + OFF_HB);
  unsigned short* WB = (unsigned short*)(ws + OFF_WB);
  unsigned short* Qb = (unsigned short*)(ws + OFF_Q);
  unsigned short* Kb = (unsigned short*)(ws + OFF_K);
  unsigned short* Vb = (unsigned short*)(ws + OFF_V);
  unsigned short* AT = (unsigned short*)(ws + OFF_ATT);
  float* cosT = (float*)(ws + OFF_COS);
  float* sinT = (float*)(ws + OFF_SIN);

  cvt_kernel<<<12288, 256, 0, stream>>>(H, Wq, Wk, Wv, Wo, HB);
  rope_tab_kernel<<<256, 256, 0, stream>>>(cosT, sinT);
  gemm8<0, 48><<<768, 512, 0, stream>>>(HB, WB, Qb, Kb, Vb);
  rope_kernel<<<32768, 256, 0, stream>>>((unsigned*)Qb, (unsigned*)Kb, cosT, sinT);
  attn_kernel<<<256, 512, 0, stream>>>(Qb, Kb, Vb, AT);
  gemm8<1, 16><<<256, 512, 0, stream>>>(AT, WB + (size_t)3 * HIDc * KC,
                                        d_out, nullptr, nullptr);
}